// Round 10
// baseline (307.584 us; speedup 1.0000x reference)
//
#include <hip/hip_runtime.h>
#include <math.h>

// Problem constants
#define BB 2
#define HH 64
#define WW 64
#define DM 192
#define DI 384
#define NS 16
#define DTR 12
#define LL 4096
#define ROWS (BB*LL)   // 8192
#define NCHUNK 128
#define LCHUNK 32      // NCHUNK*LCHUNK == LL
#define NCOMB 448      // padded combined-weight rows (416 real)
#define CSTRIDE ((size_t)BB * DI * 8)   // float2 elems per chunk slab

typedef __attribute__((ext_vector_type(8))) short bf16x8;
typedef __attribute__((ext_vector_type(4))) float f32x4;

typedef __attribute__((address_space(3))) void        as3_void;
typedef __attribute__((address_space(1))) const void  as1_cvoid;

// async global->LDS, 16B per lane; LDS dest = wave-uniform base + lane*16
__device__ __forceinline__ void gl_lds16(const unsigned short* g, unsigned short* l) {
    __builtin_amdgcn_global_load_lds((as1_cvoid*)g, (as3_void*)l, 16, 0, 0);
}

// counted-vmcnt barrier sandwich (per-wave vmcnt; uniform issue counts).
#define WAITCNT_BARRIER(N)                                         \
    do {                                                           \
        asm volatile("s_waitcnt vmcnt(" #N ")" ::: "memory");      \
        __builtin_amdgcn_s_barrier();                              \
        asm volatile("" ::: "memory");                             \
    } while (0)

__device__ __forceinline__ float silu_f(float v) {
    return v / (1.0f + __expf(-v));
}

// fp32 -> bf16 (RNE) bit trick
__device__ __forceinline__ unsigned short f2bf(float f) {
    union { float f; unsigned int u; } c; c.f = f;
    unsigned int u = c.u;
    u += 0x7fffu + ((u >> 16) & 1u);
    return (unsigned short)(u >> 16);
}
__device__ __forceinline__ float bf2f(unsigned short h) {
    union { unsigned int u; float f; } c; c.u = ((unsigned int)h) << 16;
    return c.f;
}

__device__ __forceinline__ bf16x8 f2bf8(float4 a, float4 b) {
    bf16x8 r;
    r[0] = (short)f2bf(a.x); r[1] = (short)f2bf(a.y);
    r[2] = (short)f2bf(a.z); r[3] = (short)f2bf(a.w);
    r[4] = (short)f2bf(b.x); r[5] = (short)f2bf(b.y);
    r[6] = (short)f2bf(b.z); r[7] = (short)f2bf(b.w);
    return r;
}

// ---------------------------------------------------------------------------
// Dual input GEMM + embedded weight-prep (R7 form).
// ---------------------------------------------------------------------------
__global__ __launch_bounds__(256) void gemm_in(
    const float* __restrict__ x, const float* __restrict__ cond,
    const float* __restrict__ w_in, const float* __restrict__ w_con,
    const float* __restrict__ x_proj_w, const float* __restrict__ dt_w,
    const float* __restrict__ w_out,
    unsigned short* __restrict__ xa_bf, unsigned short* __restrict__ z_bf,
    unsigned short* __restrict__ c_bf,
    unsigned short* __restrict__ wcomb_bf, unsigned short* __restrict__ w_out_bf)
{
    const int y = blockIdx.y;
    __shared__ __align__(16) unsigned short sA[2 * 64 * 32];
    __shared__ __align__(16) unsigned short sB[2 * 64 * 32];

    if (y == 18) {   // ---- prep plane ----
        const int base = blockIdx.x * 256 + threadIdx.x;
        for (int i = base; i < 18432; i += 32768) {        // W_out cast (float4)
            float4 v = ((const float4*)w_out)[i];
            ushort4 o;
            o.x = f2bf(v.x); o.y = f2bf(v.y); o.z = f2bf(v.z); o.w = f2bf(v.w);
            ((ushort4*)w_out_bf)[i] = o;
        }
        for (int e = base; e < NCOMB * DI; e += 32768) {   // combined weight
            int row = e / DI, k = e - row * DI;
            float v = 0.f;
            if (row < 384) {
                const float* dw = dt_w + row * DTR;
                #pragma unroll
                for (int r = 0; r < DTR; ++r) v += dw[r] * x_proj_w[r * DI + k];
            } else if (row < 416) {
                v = x_proj_w[(12 + (row - 384)) * DI + k];
            }
            wcomb_bf[e] = f2bf(v);
        }
        return;
    }

    const int zz = (y >= 12) ? 1 : 0;
    const float* A = zz ? cond : x;
    const float* W = zz ? w_con : w_in;
    const int bn = (zz ? (y - 12) : y) * 64;
    const int bm = blockIdx.x * 64;

    const int tid  = threadIdx.x;
    const int wave = tid >> 6;
    const int lane = tid & 63;
    const int quad = lane >> 4;
    const int l16  = lane & 15;
    const int srow = tid >> 2;                          // 0..63
    const int q4   = tid & 3;
    const int wcol = (q4 ^ ((srow >> 1) & 3)) * 8;      // swizzled write col
    const int rswz = (quad ^ ((l16 >> 1) & 3)) * 8;     // swizzled read col

    f32x4 acc[4];
    #pragma unroll
    for (int t = 0; t < 4; ++t) acc[t] = (f32x4)(0.f);

    const float* gA = &A[(size_t)(bm + srow) * DM + q4 * 8];
    const float* gB = &W[(size_t)(bn + srow) * DM + q4 * 8];

    // stage tile 0; prefetch tile 1 into regs
    float4 ra0 = *(const float4*)gA,        ra1 = *(const float4*)(gA + 4);
    float4 rb0 = *(const float4*)gB,        rb1 = *(const float4*)(gB + 4);
    *(bf16x8*)&sA[srow * 32 + wcol] = f2bf8(ra0, ra1);
    *(bf16x8*)&sB[srow * 32 + wcol] = f2bf8(rb0, rb1);
    ra0 = *(const float4*)(gA + 32); ra1 = *(const float4*)(gA + 36);
    rb0 = *(const float4*)(gB + 32); rb1 = *(const float4*)(gB + 36);

    const int ar = (wave * 16 + l16) * 32 + rswz;

    #pragma unroll
    for (int t = 0; t < 6; ++t) {
        __syncthreads();                       // buf[t&1] writes visible
        const unsigned short* cA = &sA[(t & 1) * 2048];
        const unsigned short* cB = &sB[(t & 1) * 2048];
        bf16x8 a = *(bf16x8*)&cA[ar];
        if (t + 1 < 6) {                       // write next tile to other buffer
            const int nb = (t + 1) & 1;
            *(bf16x8*)&sA[nb * 2048 + srow * 32 + wcol] = f2bf8(ra0, ra1);
            *(bf16x8*)&sB[nb * 2048 + srow * 32 + wcol] = f2bf8(rb0, rb1);
            if (t + 2 < 6) {
                const int k = (t + 2) * 32;
                ra0 = *(const float4*)(gA + k); ra1 = *(const float4*)(gA + k + 4);
                rb0 = *(const float4*)(gB + k); rb1 = *(const float4*)(gB + k + 4);
            }
        }
        #pragma unroll
        for (int n = 0; n < 4; ++n) {
            bf16x8 b = *(bf16x8*)&cB[(n * 16 + l16) * 32 + rswz];
            acc[n] = __builtin_amdgcn_mfma_f32_16x16x32_bf16(a, b, acc[n], 0, 0, 0);
        }
    }

    #pragma unroll
    for (int n = 0; n < 4; ++n) {
        int col = bn + n * 16 + l16;
        #pragma unroll
        for (int r = 0; r < 4; ++r) {
            int row = bm + wave * 16 + quad * 4 + r;
            float v = acc[n][r];
            if (zz == 0) {
                if (col < 384) xa_bf[(size_t)row * 384 + col] = f2bf(v);
                else           z_bf[(size_t)row * 384 + (col - 384)] = f2bf(silu_f(v));
            } else {
                c_bf[(size_t)row * 384 + col] = f2bf(v);
            }
        }
    }
}

// ---------------------------------------------------------------------------
// Combined GEMM, 64x64 tile, BK=32, K=384, 4-buf counted pipeline + swizzle.
// ---------------------------------------------------------------------------
__global__ __launch_bounds__(256) void gemm_comb(
    const unsigned short* __restrict__ A, const unsigned short* __restrict__ W,
    const float* __restrict__ bias, float* __restrict__ btct,
    unsigned short* __restrict__ du_lo)
{
    __shared__ __align__(16) unsigned short sA[4 * 64 * 32];
    __shared__ __align__(16) unsigned short sB[4 * 64 * 32];
    const int bm = blockIdx.x * 64;
    const int bn = blockIdx.y * 64;
    const int tid  = threadIdx.x;
    const int wave = tid >> 6;
    const int lane = tid & 63;
    const int quad = lane >> 4;
    const int l16  = lane & 15;
    const int srow = tid >> 2;
    const int scol = ((tid & 3) ^ ((tid >> 3) & 3)) * 8;
    const int rswz = (quad ^ ((l16 >> 1) & 3)) * 8;

    f32x4 acc[4];
    #pragma unroll
    for (int t = 0; t < 4; ++t) acc[t] = (f32x4)(0.f);

    const unsigned short* gA = &A[(size_t)(bm + srow) * DI + scol];
    const unsigned short* gB = &W[(size_t)(bn + srow) * DI + scol];

    #pragma unroll
    for (int p = 0; p < 3; ++p) {
        gl_lds16(gA + p * 32, &sA[p * 2048 + wave * 512]);
        gl_lds16(gB + p * 32, &sB[p * 2048 + wave * 512]);
    }
    WAITCNT_BARRIER(4);

    const int ar = (wave * 16 + l16) * 32 + rswz;

    #pragma unroll
    for (int t = 0; t < 12; ++t) {
        if (t + 3 < 12) {
            const int k = (t + 3) * 32, pb = (t + 3) & 3;
            gl_lds16(gA + k, &sA[pb * 2048 + wave * 512]);
            gl_lds16(gB + k, &sB[pb * 2048 + wave * 512]);
        }
        const unsigned short* cA = &sA[(t & 3) * 2048];
        const unsigned short* cB = &sB[(t & 3) * 2048];
        bf16x8 a = *(bf16x8*)&cA[ar];
        #pragma unroll
        for (int n = 0; n < 4; ++n) {
            bf16x8 b = *(bf16x8*)&cB[(n * 16 + l16) * 32 + rswz];
            acc[n] = __builtin_amdgcn_mfma_f32_16x16x32_bf16(a, b, acc[n], 0, 0, 0);
        }
        if (t < 11) {
            if (t + 3 < 12)      WAITCNT_BARRIER(4);
            else if (t + 2 < 12) WAITCNT_BARRIER(2);
            else                 WAITCNT_BARRIER(0);
        }
    }

    #pragma unroll
    for (int n = 0; n < 4; ++n) {
        int col = bn + n * 16 + l16;
        #pragma unroll
        for (int r = 0; r < 4; ++r) {
            int row = bm + wave * 16 + quad * 4 + r;
            float v = acc[n][r];
            if (col < 384) {
                float a = v + bias[col];
                float sp = (a > 20.f) ? a : log1pf(__expf(a));
                du_lo[((size_t)row * 384 + col) * 2] = f2bf(sp);
            } else if (col < 416) {
                int idx = col - 384;
                int pos = (idx < 16) ? ((idx & 7) * 4 + (idx >> 3))
                                     : (((idx - 16) & 7) * 4 + 2 + ((idx - 16) >> 3));
                btct[(size_t)row * 32 + pos] = v;
            }
        }
    }
}

// ---------------------------------------------------------------------------
// Fused LN + z-mul + output GEMM (R9 barrier-free form, spatial yt).
// ---------------------------------------------------------------------------
__global__ __launch_bounds__(256) void gemm_out_fused(
    const unsigned short* __restrict__ yt, const unsigned short* __restrict__ z,
    const float* __restrict__ ln_w, const float* __restrict__ ln_b,
    const unsigned short* __restrict__ W, float* __restrict__ out)
{
    __shared__ __align__(16) unsigned short sA[32 * 392];      // 25088 B
    const int bm = blockIdx.x * 32;
    const int bn = blockIdx.y * 64;
    const int tid = threadIdx.x;
    const int r2  = tid >> 3;      // 0..31 : row within tile
    const int q8  = tid & 7;       // 8 lanes per row
    const int b   = bm >> 12;      // LL = 4096
    const int l   = (bm & (LL - 1)) + r2;

    const unsigned short* yrow = yt + ((size_t)(b * LL + l)) * DI;   // spatial
    const unsigned short* zrow = z  + ((size_t)(b * LL + l)) * DI;

    // load row into registers (once), compute sums
    bf16x8 yv[6];
    float s = 0.f, s2 = 0.f;
    #pragma unroll
    for (int i = 0; i < 6; ++i) {
        yv[i] = *(const bf16x8*)&yrow[i * 64 + q8 * 8];
        #pragma unroll
        for (int e = 0; e < 8; ++e) {
            float f = bf2f((unsigned short)yv[i][e]);
            s += f; s2 += f * f;
        }
    }
    s  += __shfl_xor(s, 1);  s  += __shfl_xor(s, 2);  s  += __shfl_xor(s, 4);
    s2 += __shfl_xor(s2, 1); s2 += __shfl_xor(s2, 2); s2 += __shfl_xor(s2, 4);
    const float mu  = s * (1.0f / DI);
    const float inv = rsqrtf(s2 * (1.0f / DI) - mu * mu + 1e-5f);

    // normalize * ln affine * z -> bf16 A-tile in LDS
    #pragma unroll
    for (int i = 0; i < 6; ++i) {
        int c = i * 64 + q8 * 8;
        bf16x8 zv = *(const bf16x8*)&zrow[c];
        float4 wa = *(const float4*)&ln_w[c];
        float4 wb = *(const float4*)&ln_w[c + 4];
        float4 ba = *(const float4*)&ln_b[c];
        float4 bb = *(const float4*)&ln_b[c + 4];
        bf16x8 o;
        o[0] = (short)f2bf(((bf2f((unsigned short)yv[i][0]) - mu) * inv * wa.x + ba.x) * bf2f((unsigned short)zv[0]));
        o[1] = (short)f2bf(((bf2f((unsigned short)yv[i][1]) - mu) * inv * wa.y + ba.y) * bf2f((unsigned short)zv[1]));
        o[2] = (short)f2bf(((bf2f((unsigned short)yv[i][2]) - mu) * inv * wa.z + ba.z) * bf2f((unsigned short)zv[2]));
        o[3] = (short)f2bf(((bf2f((unsigned short)yv[i][3]) - mu) * inv * wa.w + ba.w) * bf2f((unsigned short)zv[3]));
        o[4] = (short)f2bf(((bf2f((unsigned short)yv[i][4]) - mu) * inv * wb.x + bb.x) * bf2f((unsigned short)zv[4]));
        o[5] = (short)f2bf(((bf2f((unsigned short)yv[i][5]) - mu) * inv * wb.y + bb.y) * bf2f((unsigned short)zv[5]));
        o[6] = (short)f2bf(((bf2f((unsigned short)yv[i][6]) - mu) * inv * wb.z + bb.z) * bf2f((unsigned short)zv[6]));
        o[7] = (short)f2bf(((bf2f((unsigned short)yv[i][7]) - mu) * inv * wb.w + bb.w) * bf2f((unsigned short)zv[7]));
        *(bf16x8*)&sA[r2 * 392 + c] = o;
    }

    __syncthreads();   // the ONLY barrier: sA visible to all waves

    // barrier-free MFMA K-loop: B fragments loaded straight from L2.
    const int wave = tid >> 6;
    const int lane = tid & 63;
    const int quad = lane >> 4;
    const int l16  = lane & 15;
    const int rf   = wave >> 1;          // 0..1 : row-frag
    const int np   = (wave & 1) * 2;     // n base: 0 or 2

    f32x4 acc[2];
    acc[0] = (f32x4)(0.f); acc[1] = (f32x4)(0.f);

    const unsigned short* bp0 = &W[(size_t)(bn + np * 16 + l16) * DI + quad * 8];
    const unsigned short* bp1 = bp0 + (size_t)16 * DI;
    const int abase = (rf * 16 + l16) * 392 + quad * 8;

    #pragma unroll
    for (int t = 0; t < 12; ++t) {
        bf16x8 a  = *(bf16x8*)&sA[abase + t * 32];
        bf16x8 b0 = *(const bf16x8*)(bp0 + t * 32);
        bf16x8 b1 = *(const bf16x8*)(bp1 + t * 32);
        acc[0] = __builtin_amdgcn_mfma_f32_16x16x32_bf16(a, b0, acc[0], 0, 0, 0);
        acc[1] = __builtin_amdgcn_mfma_f32_16x16x32_bf16(a, b1, acc[1], 0, 0, 0);
    }

    #pragma unroll
    for (int k = 0; k < 2; ++k) {
        int col = bn + (np + k) * 16 + l16;
        #pragma unroll
        for (int rr = 0; rr < 4; ++rr) {
            int row = bm + rf * 16 + quad * 4 + rr;
            out[(size_t)row * DM + col] = acc[k][rr];
        }
    }
}

// ---------------------------------------------------------------------------
// Fused depthwise 3x3 convs + bias + silu; scattered to scan order.
// ---------------------------------------------------------------------------
__global__ __launch_bounds__(256) void dwconv2_scatter(
    const unsigned short* __restrict__ xin, const unsigned short* __restrict__ cin,
    const float* __restrict__ wx, const float* __restrict__ bx,
    const float* __restrict__ wc, const float* __restrict__ bc,
    const int* __restrict__ rev_scan_path,
    unsigned short* __restrict__ du_hi,
    unsigned short* __restrict__ s_bf)
{
    const int tile = blockIdx.x;
    const int c0   = blockIdx.y * 32;
    const int b    = blockIdx.z;
    const int h0 = (tile >> 3) * 8, w0 = (tile & 7) * 8;
    __shared__ float smx[10 * 10 * 32];
    __shared__ float smc[10 * 10 * 32];
    __shared__ int   jtile[64];

    for (int idx = threadIdx.x; idx < 800; idx += 256) {
        int pix = idx >> 3, cq = (idx & 7) * 4;
        int py = pix / 10, px = pix - py * 10;
        int gh = h0 + py - 1, gw = w0 + px - 1;
        float4 fx = make_float4(0.f, 0.f, 0.f, 0.f);
        float4 fc = make_float4(0.f, 0.f, 0.f, 0.f);
        if (gh >= 0 && gh < 64 && gw >= 0 && gw < 64) {
            size_t g = ((size_t)(b * LL + gh * 64 + gw)) * DI + c0 + cq;
            ushort4 vx = *(const ushort4*)&xin[g];
            ushort4 vc = *(const ushort4*)&cin[g];
            fx = make_float4(bf2f(vx.x), bf2f(vx.y), bf2f(vx.z), bf2f(vx.w));
            fc = make_float4(bf2f(vc.x), bf2f(vc.y), bf2f(vc.z), bf2f(vc.w));
        }
        *(float4*)&smx[pix * 32 + cq] = fx;
        *(float4*)&smc[pix * 32 + cq] = fc;
    }
    if (threadIdx.x < 64) {
        int l = (h0 + (threadIdx.x >> 3)) * 64 + (w0 + (threadIdx.x & 7));
        jtile[threadIdx.x] = rev_scan_path[l];
    }
    __syncthreads();

    const int ch = threadIdx.x & 31;
    const int pq = threadIdx.x >> 5;   // 0..7
    float wrx[9], wrc[9];
    #pragma unroll
    for (int k = 0; k < 9; ++k) {
        wrx[k] = wx[(c0 + ch) * 9 + k];
        wrc[k] = wc[(c0 + ch) * 9 + k];
    }
    const float bvx = bx[c0 + ch];
    const float bvc = bc[c0 + ch];

    #pragma unroll
    for (int i = 0; i < 8; ++i) {
        int p  = pq * 8 + i;           // 0..63
        int ph = p >> 3, pw = p & 7;
        float ax = bvx, ac = bvc;
        #pragma unroll
        for (int ki = 0; ki < 3; ++ki)
            #pragma unroll
            for (int kj = 0; kj < 3; ++kj) {
                int si = ((ph + ki) * 10 + (pw + kj)) * 32 + ch;
                ax += wrx[ki * 3 + kj] * smx[si];
                ac += wrc[ki * 3 + kj] * smc[si];
            }
        float xv = silu_f(ax);
        float sv = xv + silu_f(ac);
        size_t o = ((size_t)(b * LL + jtile[p])) * DI + c0 + ch;
        du_hi[o * 2 + 1] = f2bf(xv);
        s_bf[o]          = f2bf(sv);
    }
}

// ---------------------------------------------------------------------------
// Pass A: per-chunk composite, register-prefetch.
// ---------------------------------------------------------------------------
__global__ __launch_bounds__(256) void scan_chunkA(
    const unsigned int* __restrict__ du, const float* __restrict__ btct,
    const float* __restrict__ A_logs,
    float* __restrict__ chunkA, float* __restrict__ chunkB)
{
    const int c = blockIdx.x;
    const int g = blockIdx.y;
    const int b = blockIdx.z;
    const int t = threadIdx.x;
    const int grp = t >> 3, p = t & 7;
    const int d = g * 32 + grp;
    const float Av0 = -__expf(A_logs[d * NS + p]);
    const float Av1 = -__expf(A_logs[d * NS + p + 8]);
    const int j0 = c * LCHUNK;

    const unsigned int* dul = du + ((size_t)b * LL + j0) * DI + d;
    const float2*       bl  = (const float2*)btct + ((size_t)b * LL + j0) * 16 + p * 2;

    float h0 = 0.f, h1 = 0.f, Sd = 0.f;
    unsigned int duv[4]; float2 bv[4];
    #pragma unroll
    for (int q = 0; q < 4; ++q) {
        duv[q] = dul[(size_t)q * DI]; bv[q] = bl[(size_t)q * 16];
    }
    for (int j = 0; j < LCHUNK; j += 4) {
        unsigned int ndu[4]; float2 nb[4];
        if (j + 4 < LCHUNK) {
            #pragma unroll
            for (int q = 0; q < 4; ++q) {
                int jj = j + 4 + q;
                ndu[q] = dul[(size_t)jj * DI]; nb[q] = bl[(size_t)jj * 16];
            }
        }
        #pragma unroll
        for (int q = 0; q < 4; ++q) {
            float dv = bf2f((unsigned short)(duv[q] & 0xffff));
            float uv = bf2f((unsigned short)(duv[q] >> 16));
            float e0 = __expf(dv * Av0);
            float e1 = __expf(dv * Av1);
            float duu = dv * uv;
            h0 = e0 * h0 + bv[q].x * duu;
            h1 = e1 * h1 + bv[q].y * duu;
            Sd += dv;
        }
        #pragma unroll
        for (int q = 0; q < 4; ++q) { duv[q]=ndu[q]; bv[q]=nb[q]; }
    }
    size_t idx = (size_t)c * CSTRIDE + ((size_t)b * DI + d) * 8 + p;
    ((float2*)chunkA)[idx] = make_float2(__expf(Sd * Av0), __expf(Sd * Av1));
    ((float2*)chunkB)[idx] = make_float2(h0, h1);
}

// ---------------------------------------------------------------------------
// Pass C: local scan seeded by inline backward fold; yt written SPATIAL.
// ---------------------------------------------------------------------------
__global__ __launch_bounds__(256) void scan_chunkC(
    const unsigned int* __restrict__ du, const float* __restrict__ btct,
    const float* __restrict__ A_logs, const float* __restrict__ Ds,
    const float* __restrict__ chunkA, const float* __restrict__ chunkB,
    const int* __restrict__ scan_path,
    unsigned short* __restrict__ yt)
{
    const int c = blockIdx.x;
    const int g = blockIdx.y;
    const int b = blockIdx.z;
    const int t = threadIdx.x;
    const int grp = t >> 3, p = t & 7;
    const int d = g * 32 + grp;
    const float Av0 = -__expf(A_logs[d * NS + p]);
    const float Av1 = -__expf(A_logs[d * NS + p + 8]);
    const float Dv = Ds[d];
    const int j0 = c * LCHUNK;

    const unsigned int* dul = du + ((size_t)b * LL + j0) * DI + d;
    const float4*       bcl = (const float4*)btct + ((size_t)b * LL + j0) * 8 + p;
    unsigned short* ytb = yt + (size_t)b * LL * DI + d;

    const size_t off = ((size_t)b * DI + d) * 8 + p;
    const float2* A2 = (const float2*)chunkA;
    const float2* B2 = (const float2*)chunkB;
    float h0 = 0.f, h1 = 0.f, P0 = 1.f, P1 = 1.f;
    for (int i = c - 1; i >= 0; --i) {
        size_t ix = (size_t)i * CSTRIDE + off;
        float2 a = A2[ix], bv = B2[ix];
        h0 += P0 * bv.x;  h1 += P1 * bv.y;
        P0 *= a.x;        P1 *= a.y;
        if (fmaxf(fabsf(P0), fabsf(P1)) < 1e-30f) break;
    }

    unsigned int duv[4]; float4 bc[4];
    #pragma unroll
    for (int q = 0; q < 4; ++q) {
        duv[q] = dul[(size_t)q * DI]; bc[q] = bcl[(size_t)q * 8];
    }
    for (int j = 0; j < LCHUNK; j += 4) {
        unsigned int ndu[4]; float4 nbc[4];
        if (j + 4 < LCHUNK) {
            #pragma unroll
            for (int q = 0; q < 4; ++q) {
                int jj = j + 4 + q;
                ndu[q] = dul[(size_t)jj * DI]; nbc[q] = bcl[(size_t)jj * 8];
            }
        }
        #pragma unroll
        for (int q = 0; q < 4; ++q) {
            float dv = bf2f((unsigned short)(duv[q] & 0xffff));
            float uv = bf2f((unsigned short)(duv[q] >> 16));
            float e0 = __expf(dv * Av0);
            float e1 = __expf(dv * Av1);
            float duu = dv * uv;
            h0 = e0 * h0 + bc[q].x * duu;
            h1 = e1 * h1 + bc[q].y * duu;
            float acc = h0 * bc[q].z + h1 * bc[q].w;
            acc += __shfl_xor(acc, 4, 8);
            acc += __shfl_xor(acc, 2, 8);
            acc += __shfl_xor(acc, 1, 8);
            if (p == 0) {
                int lsp = scan_path[j0 + j + q];
                ytb[(size_t)lsp * DI] = f2bf(acc + uv * Dv);
            }
        }
        #pragma unroll
        for (int q = 0; q < 4; ++q) { duv[q]=ndu[q]; bc[q]=nbc[q]; }
    }
}

// ---------------------------------------------------------------------------
extern "C" void kernel_launch(void* const* d_in, const int* in_sizes, int n_in,
                              void* d_out, int out_size, void* d_ws, size_t ws_size,
                              hipStream_t stream) {
    const float* x          = (const float*)d_in[0];
    const float* cond       = (const float*)d_in[1];
    const float* W_in       = (const float*)d_in[2];
    const float* W_con      = (const float*)d_in[3];
    const float* conv_w     = (const float*)d_in[4];
    const float* conv_b     = (const float*)d_in[5];
    const float* con_conv_w = (const float*)d_in[6];
    const float* con_conv_b = (const float*)d_in[7];
    const float* x_proj_w   = (const float*)d_in[8];
    const float* dt_proj_w  = (const float*)d_in[9];
    const float* dt_proj_b  = (const float*)d_in[10];
    const float* A_logs     = (const float*)d_in[11];
    const float* Ds         = (const float*)d_in[12];
    const float* ln_w       = (const float*)d_in[13];
    const float* ln_b       = (const float*)d_in[14];
    const float* W_out      = (const float*)d_in[15];
    const int*   scan_path  = (const int*)d_in[16];
    const int*   rev_path   = (const int*)d_in[17];

    float* ws = (float*)d_ws;
    const size_t S  = (size_t)BB * LL * DI;            // 3,145,728 floats
    const size_t SC = (size_t)NCHUNK * BB * DI * NS;   // 1,572,864 floats
    float* ytslab  = ws + 0 * S;                       // yt_bf (ushort, half used)
    float* zslab   = ws + 1 * S;                       // z_bf (ushort, half used)
    float* duslab  = ws + 2 * S;                       // du (uint, full slab)
    float* btct    = ws + 3 * S;                       // BB*LL*32 floats, packed
    float* chunkA  = btct + (size_t)BB * LL * 32;
    float* chunkB  = chunkA + SC;
    float* bfpool  = chunkB + SC;                      // bf16 staging area

    unsigned short* yt_bf    = (unsigned short*)ytslab;            // ROWS*DI
    unsigned short* z_bf     = (unsigned short*)zslab;             // ROWS*DI
    unsigned int*   du       = (unsigned int*)duslab;              // ROWS*DI uints
    unsigned short* s_bf     = (unsigned short*)bfpool;            // ROWS*DI
    unsigned short* xa_bf    = s_bf + (size_t)ROWS * DI;           // ROWS*DI
    unsigned short* c_bf     = xa_bf + (size_t)ROWS * DI;          // ROWS*DI
    unsigned short* w_out_bf = c_bf + (size_t)ROWS * DI;           // 192*384
    unsigned short* wcomb_bf = w_out_bf + 192 * DI;                // 448*384

    // =========== ABLATION ROUND: every stage is idempotent, so the whole
    // pipeline is launched TWICE. Output is bit-identical; the measured
    // dur_us decomposes into  T_dup = fixed + work + (warm work + gaps).
    // T_dup - 197.9 = cache-warm sum of all six kernels + 6 gaps.
    // Model W (work-dominated) predicts ~320-360 us; Model F (fixed-
    // dominated) predicts ~240-280 us. ===========
    for (int rep = 0; rep < 2; ++rep) {
        // 1) dual GEMM + embedded prep (R7 form)
        gemm_in<<<dim3(ROWS / 64, 19), 256, 0, stream>>>(
            x, cond, W_in, W_con, x_proj_w, dt_proj_w, W_out,
            xa_bf, z_bf, c_bf, wcomb_bf, w_out_bf);
        // 2) fused depthwise convs (vectorized staging) + silu + scatter
        dwconv2_scatter<<<dim3(64, 12, BB), 256, 0, stream>>>(
            xa_bf, c_bf, conv_w, conv_b, con_conv_w, con_conv_b,
            rev_path, (unsigned short*)du, s_bf);
        // 3) combined GEMM (64x64, 4-buf counted)
        gemm_comb<<<dim3(ROWS / 64, NCOMB / 64), 256, 0, stream>>>(
            s_bf, wcomb_bf, dt_proj_b, btct, (unsigned short*)du);
        // 4+5) chunked parallel scan (pass C writes yt in spatial order)
        scan_chunkA<<<dim3(NCHUNK, DI / 32, BB), 256, 0, stream>>>(
            du, btct, A_logs, chunkA, chunkB);
        scan_chunkC<<<dim3(NCHUNK, DI / 32, BB), 256, 0, stream>>>(
            du, btct, A_logs, Ds, chunkA, chunkB, scan_path, yt_bf);
        // 6) fused LN + z-mul + out GEMM (spatial yt, barrier-free K-loop)
        gemm_out_fused<<<dim3(ROWS / 32, DM / 64), 256, 0, stream>>>(
            yt_bf, z_bf, ln_w, ln_b, w_out_bf, (float*)d_out);
    }
}

// Round 11
// 288.150 us; speedup vs baseline: 1.0674x; 1.0674x over previous
//
#include <hip/hip_runtime.h>
#include <math.h>

// Problem constants
#define BB 2
#define HH 64
#define WW 64
#define DM 192
#define DI 384
#define NS 16
#define DTR 12
#define LL 4096
#define ROWS (BB*LL)   // 8192
#define NCHUNK 128
#define LCHUNK 32      // NCHUNK*LCHUNK == LL
#define NCOMB 448      // padded combined-weight rows (416 real)
#define CSTRIDE ((size_t)BB * DI * 8)   // float2 elems per chunk slab

typedef __attribute__((ext_vector_type(8))) short bf16x8;
typedef __attribute__((ext_vector_type(4))) float f32x4;

typedef __attribute__((address_space(3))) void        as3_void;
typedef __attribute__((address_space(1))) const void  as1_cvoid;

// async global->LDS, 16B per lane; LDS dest = wave-uniform base + lane*16
__device__ __forceinline__ void gl_lds16(const unsigned short* g, unsigned short* l) {
    __builtin_amdgcn_global_load_lds((as1_cvoid*)g, (as3_void*)l, 16, 0, 0);
}

__device__ __forceinline__ float silu_f(float v) {
    return v / (1.0f + __expf(-v));
}

// fp32 -> bf16 (RNE) bit trick
__device__ __forceinline__ unsigned short f2bf(float f) {
    union { float f; unsigned int u; } c; c.f = f;
    unsigned int u = c.u;
    u += 0x7fffu + ((u >> 16) & 1u);
    return (unsigned short)(u >> 16);
}
__device__ __forceinline__ float bf2f(unsigned short h) {
    union { unsigned int u; float f; } c; c.u = ((unsigned int)h) << 16;
    return c.f;
}

__device__ __forceinline__ bf16x8 f2bf8(float4 a, float4 b) {
    bf16x8 r;
    r[0] = (short)f2bf(a.x); r[1] = (short)f2bf(a.y);
    r[2] = (short)f2bf(a.z); r[3] = (short)f2bf(a.w);
    r[4] = (short)f2bf(b.x); r[5] = (short)f2bf(b.y);
    r[6] = (short)f2bf(b.z); r[7] = (short)f2bf(b.w);
    return r;
}

// ---------------------------------------------------------------------------
// Dual input GEMM, A-READ-ONCE register form + embedded weight-prep.
// Grid (256, 4), 256 thr, ZERO barriers, ZERO LDS:
//   y==0 : xa  = x @ W_in.T cols 0..383   (32-row blocks, A-frags in regs)
//   y==1 : z   = silu(x @ W_in.T cols 384..767)
//   y==2 : c   = cond @ W_con.T
//   y==3 : prep plane (wcomb build + W_out cast)
// Per wave: rf = row-frag (16 rows), q = col-half; A read ONCE into 6
// bf16x8 regs; B frags streamed from L2 (weights are L2-resident).
// Kills the 12x/6x A-panel re-read (113 MB -> 19 MB).
// MFMA lane layout identical to the R9-verified gemm_out pattern.
// ---------------------------------------------------------------------------
__global__ __launch_bounds__(256) void gemm_in(
    const float* __restrict__ x, const float* __restrict__ cond,
    const float* __restrict__ w_in, const float* __restrict__ w_con,
    const float* __restrict__ x_proj_w, const float* __restrict__ dt_w,
    const float* __restrict__ w_out,
    unsigned short* __restrict__ xa_bf, unsigned short* __restrict__ z_bf,
    unsigned short* __restrict__ c_bf,
    unsigned short* __restrict__ wcomb_bf, unsigned short* __restrict__ w_out_bf)
{
    const int y = blockIdx.y;

    if (y == 3) {   // ---- prep plane: 256 blocks x 256 thr = 65536 lanes ----
        const int base = blockIdx.x * 256 + threadIdx.x;
        for (int i = base; i < 18432; i += 65536) {        // W_out cast (float4)
            float4 v = ((const float4*)w_out)[i];
            ushort4 o;
            o.x = f2bf(v.x); o.y = f2bf(v.y); o.z = f2bf(v.z); o.w = f2bf(v.w);
            ((ushort4*)w_out_bf)[i] = o;
        }
        for (int e = base; e < NCOMB * DI; e += 65536) {   // combined weight
            int row = e / DI, k = e - row * DI;
            float v = 0.f;
            if (row < 384) {
                const float* dw = dt_w + row * DTR;
                #pragma unroll
                for (int r = 0; r < DTR; ++r) v += dw[r] * x_proj_w[r * DI + k];
            } else if (row < 416) {
                v = x_proj_w[(12 + (row - 384)) * DI + k];
            }
            wcomb_bf[e] = f2bf(v);
        }
        return;
    }

    const float* A = (y == 2) ? cond : x;
    const float* W = (y == 2) ? w_con : w_in;
    const int colbase = (y == 1) ? 384 : 0;   // offset into W rows

    const int tid  = threadIdx.x;
    const int wave = tid >> 6;
    const int lane = tid & 63;
    const int quad = lane >> 4;
    const int l16  = lane & 15;
    const int rf   = wave >> 1;          // 0..1 : row-frag within 32-row block
    const int q    = wave & 1;           // col-half (192 cols each)
    const int bm   = blockIdx.x * 32;

    // ---- A-frags: read the wave's 16 rows ONCE, fp32 -> bf16 regs ----
    const float* gA = &A[(size_t)(bm + rf * 16 + l16) * DM + quad * 8];
    bf16x8 af0 = f2bf8(*(const float4*)(gA +   0), *(const float4*)(gA +   4));
    bf16x8 af1 = f2bf8(*(const float4*)(gA +  32), *(const float4*)(gA +  36));
    bf16x8 af2 = f2bf8(*(const float4*)(gA +  64), *(const float4*)(gA +  68));
    bf16x8 af3 = f2bf8(*(const float4*)(gA +  96), *(const float4*)(gA + 100));
    bf16x8 af4 = f2bf8(*(const float4*)(gA + 128), *(const float4*)(gA + 132));
    bf16x8 af5 = f2bf8(*(const float4*)(gA + 160), *(const float4*)(gA + 164));

    f32x4 acc[12];
    #pragma unroll
    for (int i = 0; i < 12; ++i) acc[i] = (f32x4)(0.f);

    // B row for frag cf: colbase + q*192 + cf*16 + l16
    const unsigned short* gB =
        &((const unsigned short*)nullptr)[0];   // placeholder, set below
    (void)gB;

    #pragma unroll
    for (int cf = 0; cf < 12; ++cf) {
        const float* bp = &W[(size_t)(colbase + q * 192 + cf * 16 + l16) * DM + quad * 8];
        bf16x8 b0 = f2bf8(*(const float4*)(bp +   0), *(const float4*)(bp +   4));
        bf16x8 b1 = f2bf8(*(const float4*)(bp +  32), *(const float4*)(bp +  36));
        bf16x8 b2 = f2bf8(*(const float4*)(bp +  64), *(const float4*)(bp +  68));
        bf16x8 b3 = f2bf8(*(const float4*)(bp +  96), *(const float4*)(bp + 100));
        bf16x8 b4 = f2bf8(*(const float4*)(bp + 128), *(const float4*)(bp + 132));
        bf16x8 b5 = f2bf8(*(const float4*)(bp + 160), *(const float4*)(bp + 164));
        acc[cf] = __builtin_amdgcn_mfma_f32_16x16x32_bf16(af0, b0, acc[cf], 0, 0, 0);
        acc[cf] = __builtin_amdgcn_mfma_f32_16x16x32_bf16(af1, b1, acc[cf], 0, 0, 0);
        acc[cf] = __builtin_amdgcn_mfma_f32_16x16x32_bf16(af2, b2, acc[cf], 0, 0, 0);
        acc[cf] = __builtin_amdgcn_mfma_f32_16x16x32_bf16(af3, b3, acc[cf], 0, 0, 0);
        acc[cf] = __builtin_amdgcn_mfma_f32_16x16x32_bf16(af4, b4, acc[cf], 0, 0, 0);
        acc[cf] = __builtin_amdgcn_mfma_f32_16x16x32_bf16(af5, b5, acc[cf], 0, 0, 0);
    }

    #pragma unroll
    for (int cf = 0; cf < 12; ++cf) {
        int colq = q * 192 + cf * 16 + l16;     // 0..383 within this plane
        #pragma unroll
        for (int r = 0; r < 4; ++r) {
            int row = bm + rf * 16 + quad * 4 + r;
            float v = acc[cf][r];
            if (y == 0)      xa_bf[(size_t)row * 384 + colq] = f2bf(v);
            else if (y == 1) z_bf[(size_t)row * 384 + colq]  = f2bf(silu_f(v));
            else             c_bf[(size_t)row * 384 + colq]  = f2bf(v);
        }
    }
}

// ---------------------------------------------------------------------------
// Combined GEMM, A-READ-ONCE register form. Grid (256, 2), 256 thr,
// ZERO barriers, ZERO LDS. Block = 32 rows x 224-col half; per wave
// (rf, q): 16 rows x 112 cols = 7 frags. A (s_bf) read ONCE into 12
// bf16x8 regs (88 MB -> 25 MB); B (wcomb, 344 KB) streamed from L2.
// col<384 -> du_lo softplus; [384,416) -> packed btct; >=416 discard.
// ---------------------------------------------------------------------------
__global__ __launch_bounds__(256) void gemm_comb(
    const unsigned short* __restrict__ A, const unsigned short* __restrict__ W,
    const float* __restrict__ bias, float* __restrict__ btct,
    unsigned short* __restrict__ du_lo)
{
    const int tid  = threadIdx.x;
    const int wave = tid >> 6;
    const int lane = tid & 63;
    const int quad = lane >> 4;
    const int l16  = lane & 15;
    const int rf   = wave >> 1;
    const int q    = wave & 1;
    const int bm   = blockIdx.x * 32;
    const int cbase = blockIdx.y * 224 + q * 112;

    // ---- A-frags: 16 rows x K=384, read once (bf16 direct) ----
    const unsigned short* gA = &A[(size_t)(bm + rf * 16 + l16) * DI + quad * 8];
    bf16x8 af[12];
    #pragma unroll
    for (int t = 0; t < 12; ++t) af[t] = *(const bf16x8*)(gA + t * 32);

    f32x4 acc[7];
    #pragma unroll
    for (int i = 0; i < 7; ++i) acc[i] = (f32x4)(0.f);

    #pragma unroll
    for (int cf = 0; cf < 7; ++cf) {
        const unsigned short* bp = &W[(size_t)(cbase + cf * 16 + l16) * DI + quad * 8];
        #pragma unroll
        for (int t = 0; t < 12; ++t) {
            bf16x8 b = *(const bf16x8*)(bp + t * 32);
            acc[cf] = __builtin_amdgcn_mfma_f32_16x16x32_bf16(af[t], b, acc[cf], 0, 0, 0);
        }
    }

    #pragma unroll
    for (int cf = 0; cf < 7; ++cf) {
        int col = cbase + cf * 16 + l16;
        #pragma unroll
        for (int r = 0; r < 4; ++r) {
            int row = bm + rf * 16 + quad * 4 + r;
            float v = acc[cf][r];
            if (col < 384) {
                float a = v + bias[col];
                float sp = (a > 20.f) ? a : log1pf(__expf(a));
                du_lo[((size_t)row * 384 + col) * 2] = f2bf(sp);
            } else if (col < 416) {
                int idx = col - 384;
                int pos = (idx < 16) ? ((idx & 7) * 4 + (idx >> 3))
                                     : (((idx - 16) & 7) * 4 + 2 + ((idx - 16) >> 3));
                btct[(size_t)row * 32 + pos] = v;
            }
        }
    }
}

// ---------------------------------------------------------------------------
// Fused LN + z-mul + output GEMM (R9 barrier-free form, spatial yt).
// ---------------------------------------------------------------------------
__global__ __launch_bounds__(256) void gemm_out_fused(
    const unsigned short* __restrict__ yt, const unsigned short* __restrict__ z,
    const float* __restrict__ ln_w, const float* __restrict__ ln_b,
    const unsigned short* __restrict__ W, float* __restrict__ out)
{
    __shared__ __align__(16) unsigned short sA[32 * 392];      // 25088 B
    const int bm = blockIdx.x * 32;
    const int bn = blockIdx.y * 64;
    const int tid = threadIdx.x;
    const int r2  = tid >> 3;      // 0..31 : row within tile
    const int q8  = tid & 7;       // 8 lanes per row
    const int b   = bm >> 12;      // LL = 4096
    const int l   = (bm & (LL - 1)) + r2;

    const unsigned short* yrow = yt + ((size_t)(b * LL + l)) * DI;   // spatial
    const unsigned short* zrow = z  + ((size_t)(b * LL + l)) * DI;

    // load row into registers (once), compute sums
    bf16x8 yv[6];
    float s = 0.f, s2 = 0.f;
    #pragma unroll
    for (int i = 0; i < 6; ++i) {
        yv[i] = *(const bf16x8*)&yrow[i * 64 + q8 * 8];
        #pragma unroll
        for (int e = 0; e < 8; ++e) {
            float f = bf2f((unsigned short)yv[i][e]);
            s += f; s2 += f * f;
        }
    }
    s  += __shfl_xor(s, 1);  s  += __shfl_xor(s, 2);  s  += __shfl_xor(s, 4);
    s2 += __shfl_xor(s2, 1); s2 += __shfl_xor(s2, 2); s2 += __shfl_xor(s2, 4);
    const float mu  = s * (1.0f / DI);
    const float inv = rsqrtf(s2 * (1.0f / DI) - mu * mu + 1e-5f);

    // normalize * ln affine * z -> bf16 A-tile in LDS
    #pragma unroll
    for (int i = 0; i < 6; ++i) {
        int c = i * 64 + q8 * 8;
        bf16x8 zv = *(const bf16x8*)&zrow[c];
        float4 wa = *(const float4*)&ln_w[c];
        float4 wb = *(const float4*)&ln_w[c + 4];
        float4 ba = *(const float4*)&ln_b[c];
        float4 bb = *(const float4*)&ln_b[c + 4];
        bf16x8 o;
        o[0] = (short)f2bf(((bf2f((unsigned short)yv[i][0]) - mu) * inv * wa.x + ba.x) * bf2f((unsigned short)zv[0]));
        o[1] = (short)f2bf(((bf2f((unsigned short)yv[i][1]) - mu) * inv * wa.y + ba.y) * bf2f((unsigned short)zv[1]));
        o[2] = (short)f2bf(((bf2f((unsigned short)yv[i][2]) - mu) * inv * wa.z + ba.z) * bf2f((unsigned short)zv[2]));
        o[3] = (short)f2bf(((bf2f((unsigned short)yv[i][3]) - mu) * inv * wa.w + ba.w) * bf2f((unsigned short)zv[3]));
        o[4] = (short)f2bf(((bf2f((unsigned short)yv[i][4]) - mu) * inv * wb.x + bb.x) * bf2f((unsigned short)zv[4]));
        o[5] = (short)f2bf(((bf2f((unsigned short)yv[i][5]) - mu) * inv * wb.y + bb.y) * bf2f((unsigned short)zv[5]));
        o[6] = (short)f2bf(((bf2f((unsigned short)yv[i][6]) - mu) * inv * wb.z + bb.z) * bf2f((unsigned short)zv[6]));
        o[7] = (short)f2bf(((bf2f((unsigned short)yv[i][7]) - mu) * inv * wb.w + bb.w) * bf2f((unsigned short)zv[7]));
        *(bf16x8*)&sA[r2 * 392 + c] = o;
    }

    __syncthreads();   // the ONLY barrier: sA visible to all waves

    // barrier-free MFMA K-loop: B fragments loaded straight from L2.
    const int wave = tid >> 6;
    const int lane = tid & 63;
    const int quad = lane >> 4;
    const int l16  = lane & 15;
    const int rf   = wave >> 1;          // 0..1 : row-frag
    const int np   = (wave & 1) * 2;     // n base: 0 or 2

    f32x4 acc[2];
    acc[0] = (f32x4)(0.f); acc[1] = (f32x4)(0.f);

    const unsigned short* bp0 = &W[(size_t)(bn + np * 16 + l16) * DI + quad * 8];
    const unsigned short* bp1 = bp0 + (size_t)16 * DI;
    const int abase = (rf * 16 + l16) * 392 + quad * 8;

    #pragma unroll
    for (int t = 0; t < 12; ++t) {
        bf16x8 a  = *(bf16x8*)&sA[abase + t * 32];
        bf16x8 b0 = *(const bf16x8*)(bp0 + t * 32);
        bf16x8 b1 = *(const bf16x8*)(bp1 + t * 32);
        acc[0] = __builtin_amdgcn_mfma_f32_16x16x32_bf16(a, b0, acc[0], 0, 0, 0);
        acc[1] = __builtin_amdgcn_mfma_f32_16x16x32_bf16(a, b1, acc[1], 0, 0, 0);
    }

    #pragma unroll
    for (int k = 0; k < 2; ++k) {
        int col = bn + (np + k) * 16 + l16;
        #pragma unroll
        for (int rr = 0; rr < 4; ++rr) {
            int row = bm + rf * 16 + quad * 4 + rr;
            out[(size_t)row * DM + col] = acc[k][rr];
        }
    }
}

// ---------------------------------------------------------------------------
// Fused depthwise 3x3 convs + bias + silu; scattered to scan order.
// ---------------------------------------------------------------------------
__global__ __launch_bounds__(256) void dwconv2_scatter(
    const unsigned short* __restrict__ xin, const unsigned short* __restrict__ cin,
    const float* __restrict__ wx, const float* __restrict__ bx,
    const float* __restrict__ wc, const float* __restrict__ bc,
    const int* __restrict__ rev_scan_path,
    unsigned short* __restrict__ du_hi,
    unsigned short* __restrict__ s_bf)
{
    const int tile = blockIdx.x;
    const int c0   = blockIdx.y * 32;
    const int b    = blockIdx.z;
    const int h0 = (tile >> 3) * 8, w0 = (tile & 7) * 8;
    __shared__ float smx[10 * 10 * 32];
    __shared__ float smc[10 * 10 * 32];
    __shared__ int   jtile[64];

    for (int idx = threadIdx.x; idx < 800; idx += 256) {
        int pix = idx >> 3, cq = (idx & 7) * 4;
        int py = pix / 10, px = pix - py * 10;
        int gh = h0 + py - 1, gw = w0 + px - 1;
        float4 fx = make_float4(0.f, 0.f, 0.f, 0.f);
        float4 fc = make_float4(0.f, 0.f, 0.f, 0.f);
        if (gh >= 0 && gh < 64 && gw >= 0 && gw < 64) {
            size_t g = ((size_t)(b * LL + gh * 64 + gw)) * DI + c0 + cq;
            ushort4 vx = *(const ushort4*)&xin[g];
            ushort4 vc = *(const ushort4*)&cin[g];
            fx = make_float4(bf2f(vx.x), bf2f(vx.y), bf2f(vx.z), bf2f(vx.w));
            fc = make_float4(bf2f(vc.x), bf2f(vc.y), bf2f(vc.z), bf2f(vc.w));
        }
        *(float4*)&smx[pix * 32 + cq] = fx;
        *(float4*)&smc[pix * 32 + cq] = fc;
    }
    if (threadIdx.x < 64) {
        int l = (h0 + (threadIdx.x >> 3)) * 64 + (w0 + (threadIdx.x & 7));
        jtile[threadIdx.x] = rev_scan_path[l];
    }
    __syncthreads();

    const int ch = threadIdx.x & 31;
    const int pq = threadIdx.x >> 5;   // 0..7
    float wrx[9], wrc[9];
    #pragma unroll
    for (int k = 0; k < 9; ++k) {
        wrx[k] = wx[(c0 + ch) * 9 + k];
        wrc[k] = wc[(c0 + ch) * 9 + k];
    }
    const float bvx = bx[c0 + ch];
    const float bvc = bc[c0 + ch];

    #pragma unroll
    for (int i = 0; i < 8; ++i) {
        int p  = pq * 8 + i;           // 0..63
        int ph = p >> 3, pw = p & 7;
        float ax = bvx, ac = bvc;
        #pragma unroll
        for (int ki = 0; ki < 3; ++ki)
            #pragma unroll
            for (int kj = 0; kj < 3; ++kj) {
                int si = ((ph + ki) * 10 + (pw + kj)) * 32 + ch;
                ax += wrx[ki * 3 + kj] * smx[si];
                ac += wrc[ki * 3 + kj] * smc[si];
            }
        float xv = silu_f(ax);
        float sv = xv + silu_f(ac);
        size_t o = ((size_t)(b * LL + jtile[p])) * DI + c0 + ch;
        du_hi[o * 2 + 1] = f2bf(xv);
        s_bf[o]          = f2bf(sv);
    }
}

// ---------------------------------------------------------------------------
// Pass A: per-chunk composite, register-prefetch.
// ---------------------------------------------------------------------------
__global__ __launch_bounds__(256) void scan_chunkA(
    const unsigned int* __restrict__ du, const float* __restrict__ btct,
    const float* __restrict__ A_logs,
    float* __restrict__ chunkA, float* __restrict__ chunkB)
{
    const int c = blockIdx.x;
    const int g = blockIdx.y;
    const int b = blockIdx.z;
    const int t = threadIdx.x;
    const int grp = t >> 3, p = t & 7;
    const int d = g * 32 + grp;
    const float Av0 = -__expf(A_logs[d * NS + p]);
    const float Av1 = -__expf(A_logs[d * NS + p + 8]);
    const int j0 = c * LCHUNK;

    const unsigned int* dul = du + ((size_t)b * LL + j0) * DI + d;
    const float2*       bl  = (const float2*)btct + ((size_t)b * LL + j0) * 16 + p * 2;

    float h0 = 0.f, h1 = 0.f, Sd = 0.f;
    unsigned int duv[4]; float2 bv[4];
    #pragma unroll
    for (int q = 0; q < 4; ++q) {
        duv[q] = dul[(size_t)q * DI]; bv[q] = bl[(size_t)q * 16];
    }
    for (int j = 0; j < LCHUNK; j += 4) {
        unsigned int ndu[4]; float2 nb[4];
        if (j + 4 < LCHUNK) {
            #pragma unroll
            for (int q = 0; q < 4; ++q) {
                int jj = j + 4 + q;
                ndu[q] = dul[(size_t)jj * DI]; nb[q] = bl[(size_t)jj * 16];
            }
        }
        #pragma unroll
        for (int q = 0; q < 4; ++q) {
            float dv = bf2f((unsigned short)(duv[q] & 0xffff));
            float uv = bf2f((unsigned short)(duv[q] >> 16));
            float e0 = __expf(dv * Av0);
            float e1 = __expf(dv * Av1);
            float duu = dv * uv;
            h0 = e0 * h0 + bv[q].x * duu;
            h1 = e1 * h1 + bv[q].y * duu;
            Sd += dv;
        }
        #pragma unroll
        for (int q = 0; q < 4; ++q) { duv[q]=ndu[q]; bv[q]=nb[q]; }
    }
    size_t idx = (size_t)c * CSTRIDE + ((size_t)b * DI + d) * 8 + p;
    ((float2*)chunkA)[idx] = make_float2(__expf(Sd * Av0), __expf(Sd * Av1));
    ((float2*)chunkB)[idx] = make_float2(h0, h1);
}

// ---------------------------------------------------------------------------
// Pass C: local scan seeded by inline backward fold; yt written SPATIAL.
// ---------------------------------------------------------------------------
__global__ __launch_bounds__(256) void scan_chunkC(
    const unsigned int* __restrict__ du, const float* __restrict__ btct,
    const float* __restrict__ A_logs, const float* __restrict__ Ds,
    const float* __restrict__ chunkA, const float* __restrict__ chunkB,
    const int* __restrict__ scan_path,
    unsigned short* __restrict__ yt)
{
    const int c = blockIdx.x;
    const int g = blockIdx.y;
    const int b = blockIdx.z;
    const int t = threadIdx.x;
    const int grp = t >> 3, p = t & 7;
    const int d = g * 32 + grp;
    const float Av0 = -__expf(A_logs[d * NS + p]);
    const float Av1 = -__expf(A_logs[d * NS + p + 8]);
    const float Dv = Ds[d];
    const int j0 = c * LCHUNK;

    const unsigned int* dul = du + ((size_t)b * LL + j0) * DI + d;
    const float4*       bcl = (const float4*)btct + ((size_t)b * LL + j0) * 8 + p;
    unsigned short* ytb = yt + (size_t)b * LL * DI + d;

    const size_t off = ((size_t)b * DI + d) * 8 + p;
    const float2* A2 = (const float2*)chunkA;
    const float2* B2 = (const float2*)chunkB;
    float h0 = 0.f, h1 = 0.f, P0 = 1.f, P1 = 1.f;
    for (int i = c - 1; i >= 0; --i) {
        size_t ix = (size_t)i * CSTRIDE + off;
        float2 a = A2[ix], bv = B2[ix];
        h0 += P0 * bv.x;  h1 += P1 * bv.y;
        P0 *= a.x;        P1 *= a.y;
        if (fmaxf(fabsf(P0), fabsf(P1)) < 1e-30f) break;
    }

    unsigned int duv[4]; float4 bc[4];
    #pragma unroll
    for (int q = 0; q < 4; ++q) {
        duv[q] = dul[(size_t)q * DI]; bc[q] = bcl[(size_t)q * 8];
    }
    for (int j = 0; j < LCHUNK; j += 4) {
        unsigned int ndu[4]; float4 nbc[4];
        if (j + 4 < LCHUNK) {
            #pragma unroll
            for (int q = 0; q < 4; ++q) {
                int jj = j + 4 + q;
                ndu[q] = dul[(size_t)jj * DI]; nbc[q] = bcl[(size_t)jj * 8];
            }
        }
        #pragma unroll
        for (int q = 0; q < 4; ++q) {
            float dv = bf2f((unsigned short)(duv[q] & 0xffff));
            float uv = bf2f((unsigned short)(duv[q] >> 16));
            float e0 = __expf(dv * Av0);
            float e1 = __expf(dv * Av1);
            float duu = dv * uv;
            h0 = e0 * h0 + bc[q].x * duu;
            h1 = e1 * h1 + bc[q].y * duu;
            float acc = h0 * bc[q].z + h1 * bc[q].w;
            acc += __shfl_xor(acc, 4, 8);
            acc += __shfl_xor(acc, 2, 8);
            acc += __shfl_xor(acc, 1, 8);
            if (p == 0) {
                int lsp = scan_path[j0 + j + q];
                ytb[(size_t)lsp * DI] = f2bf(acc + uv * Dv);
            }
        }
        #pragma unroll
        for (int q = 0; q < 4; ++q) { duv[q]=ndu[q]; bc[q]=nbc[q]; }
    }
}

// ---------------------------------------------------------------------------
extern "C" void kernel_launch(void* const* d_in, const int* in_sizes, int n_in,
                              void* d_out, int out_size, void* d_ws, size_t ws_size,
                              hipStream_t stream) {
    const float* x          = (const float*)d_in[0];
    const float* cond       = (const float*)d_in[1];
    const float* W_in       = (const float*)d_in[2];
    const float* W_con      = (const float*)d_in[3];
    const float* conv_w     = (const float*)d_in[4];
    const float* conv_b     = (const float*)d_in[5];
    const float* con_conv_w = (const float*)d_in[6];
    const float* con_conv_b = (const float*)d_in[7];
    const float* x_proj_w   = (const float*)d_in[8];
    const float* dt_proj_w  = (const float*)d_in[9];
    const float* dt_proj_b  = (const float*)d_in[10];
    const float* A_logs     = (const float*)d_in[11];
    const float* Ds         = (const float*)d_in[12];
    const float* ln_w       = (const float*)d_in[13];
    const float* ln_b       = (const float*)d_in[14];
    const float* W_out      = (const float*)d_in[15];
    const int*   scan_path  = (const int*)d_in[16];
    const int*   rev_path   = (const int*)d_in[17];

    float* ws = (float*)d_ws;
    const size_t S  = (size_t)BB * LL * DI;            // 3,145,728 floats
    const size_t SC = (size_t)NCHUNK * BB * DI * NS;   // 1,572,864 floats
    float* ytslab  = ws + 0 * S;                       // yt_bf (ushort, half used)
    float* zslab   = ws + 1 * S;                       // z_bf (ushort, half used)
    float* duslab  = ws + 2 * S;                       // du (uint, full slab)
    float* btct    = ws + 3 * S;                       // BB*LL*32 floats, packed
    float* chunkA  = btct + (size_t)BB * LL * 32;
    float* chunkB  = chunkA + SC;
    float* bfpool  = chunkB + SC;                      // bf16 staging area

    unsigned short* yt_bf    = (unsigned short*)ytslab;            // ROWS*DI
    unsigned short* z_bf     = (unsigned short*)zslab;             // ROWS*DI
    unsigned int*   du       = (unsigned int*)duslab;              // ROWS*DI uints
    unsigned short* s_bf     = (unsigned short*)bfpool;            // ROWS*DI
    unsigned short* xa_bf    = s_bf + (size_t)ROWS * DI;           // ROWS*DI
    unsigned short* c_bf     = xa_bf + (size_t)ROWS * DI;          // ROWS*DI
    unsigned short* w_out_bf = c_bf + (size_t)ROWS * DI;           // 192*384
    unsigned short* wcomb_bf = w_out_bf + 192 * DI;                // 448*384

    // 1) dual GEMM, A-read-once register form + embedded prep
    gemm_in<<<dim3(ROWS / 32, 4), 256, 0, stream>>>(
        x, cond, W_in, W_con, x_proj_w, dt_proj_w, W_out,
        xa_bf, z_bf, c_bf, wcomb_bf, w_out_bf);
    // 2) fused depthwise convs (vectorized staging) + silu + scatter
    dwconv2_scatter<<<dim3(64, 12, BB), 256, 0, stream>>>(
        xa_bf, c_bf, conv_w, conv_b, con_conv_w, con_conv_b,
        rev_path, (unsigned short*)du, s_bf);
    // 3) combined GEMM, A-read-once register form (zero barriers)
    gemm_comb<<<dim3(ROWS / 32, 2), 256, 0, stream>>>(
        s_bf, wcomb_bf, dt_proj_b, btct, (unsigned short*)du);
    // 4+5) chunked parallel scan (pass C writes yt in spatial order)
    scan_chunkA<<<dim3(NCHUNK, DI / 32, BB), 256, 0, stream>>>(
        du, btct, A_logs, chunkA, chunkB);
    scan_chunkC<<<dim3(NCHUNK, DI / 32, BB), 256, 0, stream>>>(
        du, btct, A_logs, Ds, chunkA, chunkB, scan_path, yt_bf);
    // 6) fused LN + z-mul + out GEMM (spatial yt, barrier-free K-loop)
    gemm_out_fused<<<dim3(ROWS / 32, DM / 64), 256, 0, stream>>>(
        yt_bf, z_bf, ln_w, ln_b, w_out_bf, (float*)d_out);
}

// Round 12
// 196.371 us; speedup vs baseline: 1.5663x; 1.4674x over previous
//
#include <hip/hip_runtime.h>
#include <math.h>

// Problem constants
#define BB 2
#define HH 64
#define WW 64
#define DM 192
#define DI 384
#define NS 16
#define DTR 12
#define LL 4096
#define ROWS (BB*LL)   // 8192
#define NCHUNK 128
#define LCHUNK 32      // NCHUNK*LCHUNK == LL
#define NCOMB 448      // padded combined-weight rows (416 real)
#define CSTRIDE ((size_t)BB * DI * 8)   // float2 elems per chunk slab

typedef __attribute__((ext_vector_type(8))) short bf16x8;
typedef __attribute__((ext_vector_type(4))) float f32x4;

typedef __attribute__((address_space(3))) void        as3_void;
typedef __attribute__((address_space(1))) const void  as1_cvoid;

// async global->LDS, 16B per lane; LDS dest = wave-uniform base + lane*16
__device__ __forceinline__ void gl_lds16(const unsigned short* g, unsigned short* l) {
    __builtin_amdgcn_global_load_lds((as1_cvoid*)g, (as3_void*)l, 16, 0, 0);
}

// counted-vmcnt barrier sandwich (per-wave vmcnt; uniform issue counts).
#define WAITCNT_BARRIER(N)                                         \
    do {                                                           \
        asm volatile("s_waitcnt vmcnt(" #N ")" ::: "memory");      \
        __builtin_amdgcn_s_barrier();                              \
        asm volatile("" ::: "memory");                             \
    } while (0)

__device__ __forceinline__ float silu_f(float v) {
    return v / (1.0f + __expf(-v));
}

// fp32 -> bf16 (RNE) bit trick
__device__ __forceinline__ unsigned short f2bf(float f) {
    union { float f; unsigned int u; } c; c.f = f;
    unsigned int u = c.u;
    u += 0x7fffu + ((u >> 16) & 1u);
    return (unsigned short)(u >> 16);
}
__device__ __forceinline__ float bf2f(unsigned short h) {
    union { unsigned int u; float f; } c; c.u = ((unsigned int)h) << 16;
    return c.f;
}

__device__ __forceinline__ bf16x8 f2bf8(float4 a, float4 b) {
    bf16x8 r;
    r[0] = (short)f2bf(a.x); r[1] = (short)f2bf(a.y);
    r[2] = (short)f2bf(a.z); r[3] = (short)f2bf(a.w);
    r[4] = (short)f2bf(b.x); r[5] = (short)f2bf(b.y);
    r[6] = (short)f2bf(b.z); r[7] = (short)f2bf(b.w);
    return r;
}

// ---------------------------------------------------------------------------
// Dual input GEMM + embedded weight-prep (R7 form — best measured, 197.46).
// Grid (128, 19), 256 thr:
//   y 0..11  : xz = x @ W_in.T (xa->bf16, z->silu bf16), 64x64 tiles
//   y 12..17 : c = cond @ W_con.T (bf16)
//   y == 18  : build wcomb[448][384] bf16 + cast W_out -> bf16
// A and B reg-staged from fp32 with inline bf16 cast, 2-buffer LDS,
// ONE barrier per K-iter, XOR bank swizzle. 16 KB LDS -> 8 blocks/CU.
// ---------------------------------------------------------------------------
__global__ __launch_bounds__(256) void gemm_in(
    const float* __restrict__ x, const float* __restrict__ cond,
    const float* __restrict__ w_in, const float* __restrict__ w_con,
    const float* __restrict__ x_proj_w, const float* __restrict__ dt_w,
    const float* __restrict__ w_out,
    unsigned short* __restrict__ xa_bf, unsigned short* __restrict__ z_bf,
    unsigned short* __restrict__ c_bf,
    unsigned short* __restrict__ wcomb_bf, unsigned short* __restrict__ w_out_bf)
{
    const int y = blockIdx.y;
    __shared__ __align__(16) unsigned short sA[2 * 64 * 32];
    __shared__ __align__(16) unsigned short sB[2 * 64 * 32];

    if (y == 18) {   // ---- prep plane: 128 blocks x 256 thr = 32768 lanes ----
        const int base = blockIdx.x * 256 + threadIdx.x;
        for (int i = base; i < 18432; i += 32768) {        // W_out cast (float4)
            float4 v = ((const float4*)w_out)[i];
            ushort4 o;
            o.x = f2bf(v.x); o.y = f2bf(v.y); o.z = f2bf(v.z); o.w = f2bf(v.w);
            ((ushort4*)w_out_bf)[i] = o;
        }
        for (int e = base; e < NCOMB * DI; e += 32768) {   // combined weight
            int row = e / DI, k = e - row * DI;
            float v = 0.f;
            if (row < 384) {
                const float* dw = dt_w + row * DTR;
                #pragma unroll
                for (int r = 0; r < DTR; ++r) v += dw[r] * x_proj_w[r * DI + k];
            } else if (row < 416) {
                v = x_proj_w[(12 + (row - 384)) * DI + k];
            }
            wcomb_bf[e] = f2bf(v);
        }
        return;
    }

    const int zz = (y >= 12) ? 1 : 0;
    const float* A = zz ? cond : x;
    const float* W = zz ? w_con : w_in;
    const int bn = (zz ? (y - 12) : y) * 64;
    const int bm = blockIdx.x * 64;

    const int tid  = threadIdx.x;
    const int wave = tid >> 6;
    const int lane = tid & 63;
    const int quad = lane >> 4;
    const int l16  = lane & 15;
    const int srow = tid >> 2;                          // 0..63
    const int q4   = tid & 3;
    const int wcol = (q4 ^ ((srow >> 1) & 3)) * 8;      // swizzled write col
    const int rswz = (quad ^ ((l16 >> 1) & 3)) * 8;     // swizzled read col

    f32x4 acc[4];
    #pragma unroll
    for (int t = 0; t < 4; ++t) acc[t] = (f32x4)(0.f);

    const float* gA = &A[(size_t)(bm + srow) * DM + q4 * 8];
    const float* gB = &W[(size_t)(bn + srow) * DM + q4 * 8];

    // stage tile 0; prefetch tile 1 into regs
    float4 ra0 = *(const float4*)gA,        ra1 = *(const float4*)(gA + 4);
    float4 rb0 = *(const float4*)gB,        rb1 = *(const float4*)(gB + 4);
    *(bf16x8*)&sA[srow * 32 + wcol] = f2bf8(ra0, ra1);
    *(bf16x8*)&sB[srow * 32 + wcol] = f2bf8(rb0, rb1);
    ra0 = *(const float4*)(gA + 32); ra1 = *(const float4*)(gA + 36);
    rb0 = *(const float4*)(gB + 32); rb1 = *(const float4*)(gB + 36);

    const int ar = (wave * 16 + l16) * 32 + rswz;

    #pragma unroll
    for (int t = 0; t < 6; ++t) {
        __syncthreads();                       // buf[t&1] writes visible
        const unsigned short* cA = &sA[(t & 1) * 2048];
        const unsigned short* cB = &sB[(t & 1) * 2048];
        bf16x8 a = *(bf16x8*)&cA[ar];
        if (t + 1 < 6) {                       // write next tile to other buffer
            const int nb = (t + 1) & 1;
            *(bf16x8*)&sA[nb * 2048 + srow * 32 + wcol] = f2bf8(ra0, ra1);
            *(bf16x8*)&sB[nb * 2048 + srow * 32 + wcol] = f2bf8(rb0, rb1);
            if (t + 2 < 6) {
                const int k = (t + 2) * 32;
                ra0 = *(const float4*)(gA + k); ra1 = *(const float4*)(gA + k + 4);
                rb0 = *(const float4*)(gB + k); rb1 = *(const float4*)(gB + k + 4);
            }
        }
        #pragma unroll
        for (int n = 0; n < 4; ++n) {
            bf16x8 b = *(bf16x8*)&cB[(n * 16 + l16) * 32 + rswz];
            acc[n] = __builtin_amdgcn_mfma_f32_16x16x32_bf16(a, b, acc[n], 0, 0, 0);
        }
    }

    #pragma unroll
    for (int n = 0; n < 4; ++n) {
        int col = bn + n * 16 + l16;
        #pragma unroll
        for (int r = 0; r < 4; ++r) {
            int row = bm + wave * 16 + quad * 4 + r;
            float v = acc[n][r];
            if (zz == 0) {
                if (col < 384) xa_bf[(size_t)row * 384 + col] = f2bf(v);
                else           z_bf[(size_t)row * 384 + (col - 384)] = f2bf(silu_f(v));
            } else {
                c_bf[(size_t)row * 384 + col] = f2bf(v);
            }
        }
    }
}

// ---------------------------------------------------------------------------
// Combined GEMM, 64x64 tile, BK=32, K=384 (12 K-tiles), 4-buf counted
// pipeline + swizzle. Grid (128, 7) = 896 blocks (fully co-resident).
// col<384 -> du_lo softplus; [384,416) -> packed btct.
// ---------------------------------------------------------------------------
__global__ __launch_bounds__(256) void gemm_comb(
    const unsigned short* __restrict__ A, const unsigned short* __restrict__ W,
    const float* __restrict__ bias, float* __restrict__ btct,
    unsigned short* __restrict__ du_lo)
{
    __shared__ __align__(16) unsigned short sA[4 * 64 * 32];
    __shared__ __align__(16) unsigned short sB[4 * 64 * 32];
    const int bm = blockIdx.x * 64;
    const int bn = blockIdx.y * 64;
    const int tid  = threadIdx.x;
    const int wave = tid >> 6;
    const int lane = tid & 63;
    const int quad = lane >> 4;
    const int l16  = lane & 15;
    const int srow = tid >> 2;
    const int scol = ((tid & 3) ^ ((tid >> 3) & 3)) * 8;
    const int rswz = (quad ^ ((l16 >> 1) & 3)) * 8;

    f32x4 acc[4];
    #pragma unroll
    for (int t = 0; t < 4; ++t) acc[t] = (f32x4)(0.f);

    const unsigned short* gA = &A[(size_t)(bm + srow) * DI + scol];
    const unsigned short* gB = &W[(size_t)(bn + srow) * DI + scol];

    #pragma unroll
    for (int p = 0; p < 3; ++p) {
        gl_lds16(gA + p * 32, &sA[p * 2048 + wave * 512]);
        gl_lds16(gB + p * 32, &sB[p * 2048 + wave * 512]);
    }
    WAITCNT_BARRIER(4);

    const int ar = (wave * 16 + l16) * 32 + rswz;

    #pragma unroll
    for (int t = 0; t < 12; ++t) {
        if (t + 3 < 12) {
            const int k = (t + 3) * 32, pb = (t + 3) & 3;
            gl_lds16(gA + k, &sA[pb * 2048 + wave * 512]);
            gl_lds16(gB + k, &sB[pb * 2048 + wave * 512]);
        }
        const unsigned short* cA = &sA[(t & 3) * 2048];
        const unsigned short* cB = &sB[(t & 3) * 2048];
        bf16x8 a = *(bf16x8*)&cA[ar];
        #pragma unroll
        for (int n = 0; n < 4; ++n) {
            bf16x8 b = *(bf16x8*)&cB[(n * 16 + l16) * 32 + rswz];
            acc[n] = __builtin_amdgcn_mfma_f32_16x16x32_bf16(a, b, acc[n], 0, 0, 0);
        }
        if (t < 11) {
            if (t + 3 < 12)      WAITCNT_BARRIER(4);
            else if (t + 2 < 12) WAITCNT_BARRIER(2);
            else                 WAITCNT_BARRIER(0);
        }
    }

    #pragma unroll
    for (int n = 0; n < 4; ++n) {
        int col = bn + n * 16 + l16;
        #pragma unroll
        for (int r = 0; r < 4; ++r) {
            int row = bm + wave * 16 + quad * 4 + r;
            float v = acc[n][r];
            if (col < 384) {
                float a = v + bias[col];
                float sp = (a > 20.f) ? a : log1pf(__expf(a));
                du_lo[((size_t)row * 384 + col) * 2] = f2bf(sp);
            } else if (col < 416) {
                int idx = col - 384;
                int pos = (idx < 16) ? ((idx & 7) * 4 + (idx >> 3))
                                     : (((idx - 16) & 7) * 4 + 2 + ((idx - 16) >> 3));
                btct[(size_t)row * 32 + pos] = v;
            }
        }
    }
}

// ---------------------------------------------------------------------------
// Fused LN + z-mul + output GEMM. 32-row tiles: grid (256, 3), 256 thr.
// LN held in registers (single yt read); A-tile in padded LDS [32][392];
// B staged via 3-buffer counted lds-direct. out = LN(yt[rev])*z @ W_out.T.
// ---------------------------------------------------------------------------
__global__ __launch_bounds__(256) void gemm_out_fused(
    const unsigned short* __restrict__ yt, const unsigned short* __restrict__ z,
    const int* __restrict__ rev_path,
    const float* __restrict__ ln_w, const float* __restrict__ ln_b,
    const unsigned short* __restrict__ W, float* __restrict__ out)
{
    __shared__ __align__(16) unsigned short sA[32 * 392];      // 25088 B
    __shared__ __align__(16) unsigned short sB[3 * 64 * 32];   // 12288 B
    const int bm = blockIdx.x * 32;
    const int bn = blockIdx.y * 64;
    const int tid = threadIdx.x;
    const int r2  = tid >> 3;      // 0..31 : row within tile
    const int q8  = tid & 7;       // 8 lanes per row
    const int b   = bm >> 12;      // LL = 4096
    const int l   = (bm & (LL - 1)) + r2;
    const int js  = rev_path[l];

    const unsigned short* yrow = yt + ((size_t)(b * LL + js)) * DI;
    const unsigned short* zrow = z  + ((size_t)(b * LL + l)) * DI;

    // load row into registers (once), compute sums
    bf16x8 yv[6];
    float s = 0.f, s2 = 0.f;
    #pragma unroll
    for (int i = 0; i < 6; ++i) {
        yv[i] = *(const bf16x8*)&yrow[i * 64 + q8 * 8];
        #pragma unroll
        for (int e = 0; e < 8; ++e) {
            float f = bf2f((unsigned short)yv[i][e]);
            s += f; s2 += f * f;
        }
    }
    s  += __shfl_xor(s, 1);  s  += __shfl_xor(s, 2);  s  += __shfl_xor(s, 4);
    s2 += __shfl_xor(s2, 1); s2 += __shfl_xor(s2, 2); s2 += __shfl_xor(s2, 4);
    const float mu  = s * (1.0f / DI);
    const float inv = rsqrtf(s2 * (1.0f / DI) - mu * mu + 1e-5f);

    // normalize * ln affine * z -> bf16 A-tile in LDS
    #pragma unroll
    for (int i = 0; i < 6; ++i) {
        int c = i * 64 + q8 * 8;
        bf16x8 zv = *(const bf16x8*)&zrow[c];
        float4 wa = *(const float4*)&ln_w[c];
        float4 wb = *(const float4*)&ln_w[c + 4];
        float4 ba = *(const float4*)&ln_b[c];
        float4 bb = *(const float4*)&ln_b[c + 4];
        bf16x8 o;
        o[0] = (short)f2bf(((bf2f((unsigned short)yv[i][0]) - mu) * inv * wa.x + ba.x) * bf2f((unsigned short)zv[0]));
        o[1] = (short)f2bf(((bf2f((unsigned short)yv[i][1]) - mu) * inv * wa.y + ba.y) * bf2f((unsigned short)zv[1]));
        o[2] = (short)f2bf(((bf2f((unsigned short)yv[i][2]) - mu) * inv * wa.z + ba.z) * bf2f((unsigned short)zv[2]));
        o[3] = (short)f2bf(((bf2f((unsigned short)yv[i][3]) - mu) * inv * wa.w + ba.w) * bf2f((unsigned short)zv[3]));
        o[4] = (short)f2bf(((bf2f((unsigned short)yv[i][4]) - mu) * inv * wb.x + bb.x) * bf2f((unsigned short)zv[4]));
        o[5] = (short)f2bf(((bf2f((unsigned short)yv[i][5]) - mu) * inv * wb.y + bb.y) * bf2f((unsigned short)zv[5]));
        o[6] = (short)f2bf(((bf2f((unsigned short)yv[i][6]) - mu) * inv * wb.z + bb.z) * bf2f((unsigned short)zv[6]));
        o[7] = (short)f2bf(((bf2f((unsigned short)yv[i][7]) - mu) * inv * wb.w + bb.w) * bf2f((unsigned short)zv[7]));
        *(bf16x8*)&sA[r2 * 392 + c] = o;
    }

    // MFMA K-loop: 3-buffer counted B staging. wave -> (rf, n-pair).
    const int wave = tid >> 6;
    const int lane = tid & 63;
    const int quad = lane >> 4;
    const int l16  = lane & 15;
    const int srow = tid >> 2;
    const int scol = ((tid & 3) ^ ((tid >> 3) & 3)) * 8;
    const int rswz = (quad ^ ((l16 >> 1) & 3)) * 8;
    const int rf   = wave >> 1;          // 0..1 : row-frag
    const int np   = (wave & 1) * 2;     // n base: 0 or 2

    f32x4 acc[2];
    acc[0] = (f32x4)(0.f); acc[1] = (f32x4)(0.f);

    const unsigned short* gB = &W[(size_t)(bn + srow) * DI + scol];
    const int abase = (rf * 16 + l16) * 392 + quad * 8;

    gl_lds16(gB,      &sB[0 * 2048 + wave * 512]);
    gl_lds16(gB + 32, &sB[1 * 2048 + wave * 512]);
    __syncthreads();   // drains A ds_writes + B tiles 0,1

    #pragma unroll
    for (int t = 0; t < 12; ++t) {
        if (t + 2 < 12)
            gl_lds16(gB + (t + 2) * 32, &sB[((t + 2) % 3) * 2048 + wave * 512]);
        bf16x8 a = *(bf16x8*)&sA[abase + t * 32];
        const unsigned short* cB = &sB[(t % 3) * 2048];
        #pragma unroll
        for (int k = 0; k < 2; ++k) {
            bf16x8 bfr = *(bf16x8*)&cB[((np + k) * 16 + l16) * 32 + rswz];
            acc[k] = __builtin_amdgcn_mfma_f32_16x16x32_bf16(a, bfr, acc[k], 0, 0, 0);
        }
        if (t < 11) {
            if (t + 2 < 12) WAITCNT_BARRIER(1);
            else            WAITCNT_BARRIER(0);
        }
    }

    #pragma unroll
    for (int k = 0; k < 2; ++k) {
        int col = bn + (np + k) * 16 + l16;
        #pragma unroll
        for (int rr = 0; rr < 4; ++rr) {
            int row = bm + rf * 16 + quad * 4 + rr;
            out[(size_t)row * DM + col] = acc[k][rr];
        }
    }
}

// ---------------------------------------------------------------------------
// Fused depthwise 3x3 convs + bias + silu; inputs bf16 (ushort4-vectorized
// staging), math fp32; writes u -> HIGH ushort of du, s (bf16), scattered to
// scan order. 32-channel groups; grid (64, 12, B).
// ---------------------------------------------------------------------------
__global__ __launch_bounds__(256) void dwconv2_scatter(
    const unsigned short* __restrict__ xin, const unsigned short* __restrict__ cin,
    const float* __restrict__ wx, const float* __restrict__ bx,
    const float* __restrict__ wc, const float* __restrict__ bc,
    const int* __restrict__ rev_scan_path,
    unsigned short* __restrict__ du_hi,
    unsigned short* __restrict__ s_bf)
{
    const int tile = blockIdx.x;
    const int c0   = blockIdx.y * 32;
    const int b    = blockIdx.z;
    const int h0 = (tile >> 3) * 8, w0 = (tile & 7) * 8;
    __shared__ float smx[10 * 10 * 32];
    __shared__ float smc[10 * 10 * 32];
    __shared__ int   jtile[64];

    for (int idx = threadIdx.x; idx < 800; idx += 256) {
        int pix = idx >> 3, cq = (idx & 7) * 4;
        int py = pix / 10, px = pix - py * 10;
        int gh = h0 + py - 1, gw = w0 + px - 1;
        float4 fx = make_float4(0.f, 0.f, 0.f, 0.f);
        float4 fc = make_float4(0.f, 0.f, 0.f, 0.f);
        if (gh >= 0 && gh < 64 && gw >= 0 && gw < 64) {
            size_t g = ((size_t)(b * LL + gh * 64 + gw)) * DI + c0 + cq;
            ushort4 vx = *(const ushort4*)&xin[g];
            ushort4 vc = *(const ushort4*)&cin[g];
            fx = make_float4(bf2f(vx.x), bf2f(vx.y), bf2f(vx.z), bf2f(vx.w));
            fc = make_float4(bf2f(vc.x), bf2f(vc.y), bf2f(vc.z), bf2f(vc.w));
        }
        *(float4*)&smx[pix * 32 + cq] = fx;
        *(float4*)&smc[pix * 32 + cq] = fc;
    }
    if (threadIdx.x < 64) {
        int l = (h0 + (threadIdx.x >> 3)) * 64 + (w0 + (threadIdx.x & 7));
        jtile[threadIdx.x] = rev_scan_path[l];
    }
    __syncthreads();

    const int ch = threadIdx.x & 31;
    const int pq = threadIdx.x >> 5;   // 0..7
    float wrx[9], wrc[9];
    #pragma unroll
    for (int k = 0; k < 9; ++k) {
        wrx[k] = wx[(c0 + ch) * 9 + k];
        wrc[k] = wc[(c0 + ch) * 9 + k];
    }
    const float bvx = bx[c0 + ch];
    const float bvc = bc[c0 + ch];

    #pragma unroll
    for (int i = 0; i < 8; ++i) {
        int p  = pq * 8 + i;           // 0..63
        int ph = p >> 3, pw = p & 7;
        float ax = bvx, ac = bvc;
        #pragma unroll
        for (int ki = 0; ki < 3; ++ki)
            #pragma unroll
            for (int kj = 0; kj < 3; ++kj) {
                int si = ((ph + ki) * 10 + (pw + kj)) * 32 + ch;
                ax += wrx[ki * 3 + kj] * smx[si];
                ac += wrc[ki * 3 + kj] * smc[si];
            }
        float xv = silu_f(ax);
        float sv = xv + silu_f(ac);
        size_t o = ((size_t)(b * LL + jtile[p])) * DI + c0 + ch;
        du_hi[o * 2 + 1] = f2bf(xv);
        s_bf[o]          = f2bf(sv);
    }
}

// ---------------------------------------------------------------------------
// Pass A: per-chunk composite, register-prefetch.
// ---------------------------------------------------------------------------
__global__ __launch_bounds__(256) void scan_chunkA(
    const unsigned int* __restrict__ du, const float* __restrict__ btct,
    const float* __restrict__ A_logs,
    float* __restrict__ chunkA, float* __restrict__ chunkB)
{
    const int c = blockIdx.x;
    const int g = blockIdx.y;
    const int b = blockIdx.z;
    const int t = threadIdx.x;
    const int grp = t >> 3, p = t & 7;
    const int d = g * 32 + grp;
    const float Av0 = -__expf(A_logs[d * NS + p]);
    const float Av1 = -__expf(A_logs[d * NS + p + 8]);
    const int j0 = c * LCHUNK;

    const unsigned int* dul = du + ((size_t)b * LL + j0) * DI + d;
    const float2*       bl  = (const float2*)btct + ((size_t)b * LL + j0) * 16 + p * 2;

    float h0 = 0.f, h1 = 0.f, Sd = 0.f;
    unsigned int duv[4]; float2 bv[4];
    #pragma unroll
    for (int q = 0; q < 4; ++q) {
        duv[q] = dul[(size_t)q * DI]; bv[q] = bl[(size_t)q * 16];
    }
    for (int j = 0; j < LCHUNK; j += 4) {
        unsigned int ndu[4]; float2 nb[4];
        if (j + 4 < LCHUNK) {
            #pragma unroll
            for (int q = 0; q < 4; ++q) {
                int jj = j + 4 + q;
                ndu[q] = dul[(size_t)jj * DI]; nb[q] = bl[(size_t)jj * 16];
            }
        }
        #pragma unroll
        for (int q = 0; q < 4; ++q) {
            float dv = bf2f((unsigned short)(duv[q] & 0xffff));
            float uv = bf2f((unsigned short)(duv[q] >> 16));
            float e0 = __expf(dv * Av0);
            float e1 = __expf(dv * Av1);
            float duu = dv * uv;
            h0 = e0 * h0 + bv[q].x * duu;
            h1 = e1 * h1 + bv[q].y * duu;
            Sd += dv;
        }
        #pragma unroll
        for (int q = 0; q < 4; ++q) { duv[q]=ndu[q]; bv[q]=nb[q]; }
    }
    size_t idx = (size_t)c * CSTRIDE + ((size_t)b * DI + d) * 8 + p;
    ((float2*)chunkA)[idx] = make_float2(__expf(Sd * Av0), __expf(Sd * Av1));
    ((float2*)chunkB)[idx] = make_float2(h0, h1);
}

// ---------------------------------------------------------------------------
// Pass C: local scan seeded by inline backward fold over composites.
// ---------------------------------------------------------------------------
__global__ __launch_bounds__(256) void scan_chunkC(
    const unsigned int* __restrict__ du, const float* __restrict__ btct,
    const float* __restrict__ A_logs, const float* __restrict__ Ds,
    const float* __restrict__ chunkA, const float* __restrict__ chunkB,
    unsigned short* __restrict__ yt)
{
    const int c = blockIdx.x;
    const int g = blockIdx.y;
    const int b = blockIdx.z;
    const int t = threadIdx.x;
    const int grp = t >> 3, p = t & 7;
    const int d = g * 32 + grp;
    const float Av0 = -__expf(A_logs[d * NS + p]);
    const float Av1 = -__expf(A_logs[d * NS + p + 8]);
    const float Dv = Ds[d];
    const int j0 = c * LCHUNK;

    const unsigned int* dul = du + ((size_t)b * LL + j0) * DI + d;
    const float4*       bcl = (const float4*)btct + ((size_t)b * LL + j0) * 8 + p;
    unsigned short* yl = yt + ((size_t)b * LL + j0) * DI + d;

    const size_t off = ((size_t)b * DI + d) * 8 + p;
    const float2* A2 = (const float2*)chunkA;
    const float2* B2 = (const float2*)chunkB;
    float h0 = 0.f, h1 = 0.f, P0 = 1.f, P1 = 1.f;
    for (int i = c - 1; i >= 0; --i) {
        size_t ix = (size_t)i * CSTRIDE + off;
        float2 a = A2[ix], bv = B2[ix];
        h0 += P0 * bv.x;  h1 += P1 * bv.y;
        P0 *= a.x;        P1 *= a.y;
        if (fmaxf(fabsf(P0), fabsf(P1)) < 1e-30f) break;
    }

    unsigned int duv[4]; float4 bc[4];
    #pragma unroll
    for (int q = 0; q < 4; ++q) {
        duv[q] = dul[(size_t)q * DI]; bc[q] = bcl[(size_t)q * 8];
    }
    for (int j = 0; j < LCHUNK; j += 4) {
        unsigned int ndu[4]; float4 nbc[4];
        if (j + 4 < LCHUNK) {
            #pragma unroll
            for (int q = 0; q < 4; ++q) {
                int jj = j + 4 + q;
                ndu[q] = dul[(size_t)jj * DI]; nbc[q] = bcl[(size_t)jj * 8];
            }
        }
        #pragma unroll
        for (int q = 0; q < 4; ++q) {
            float dv = bf2f((unsigned short)(duv[q] & 0xffff));
            float uv = bf2f((unsigned short)(duv[q] >> 16));
            float e0 = __expf(dv * Av0);
            float e1 = __expf(dv * Av1);
            float duu = dv * uv;
            h0 = e0 * h0 + bc[q].x * duu;
            h1 = e1 * h1 + bc[q].y * duu;
            float acc = h0 * bc[q].z + h1 * bc[q].w;
            acc += __shfl_xor(acc, 4, 8);
            acc += __shfl_xor(acc, 2, 8);
            acc += __shfl_xor(acc, 1, 8);
            if (p == 0) yl[(size_t)(j + q) * DI] = f2bf(acc + uv * Dv);
        }
        #pragma unroll
        for (int q = 0; q < 4; ++q) { duv[q]=ndu[q]; bc[q]=nbc[q]; }
    }
}

// ---------------------------------------------------------------------------
extern "C" void kernel_launch(void* const* d_in, const int* in_sizes, int n_in,
                              void* d_out, int out_size, void* d_ws, size_t ws_size,
                              hipStream_t stream) {
    const float* x          = (const float*)d_in[0];
    const float* cond       = (const float*)d_in[1];
    const float* W_in       = (const float*)d_in[2];
    const float* W_con      = (const float*)d_in[3];
    const float* conv_w     = (const float*)d_in[4];
    const float* conv_b     = (const float*)d_in[5];
    const float* con_conv_w = (const float*)d_in[6];
    const float* con_conv_b = (const float*)d_in[7];
    const float* x_proj_w   = (const float*)d_in[8];
    const float* dt_proj_w  = (const float*)d_in[9];
    const float* dt_proj_b  = (const float*)d_in[10];
    const float* A_logs     = (const float*)d_in[11];
    const float* Ds         = (const float*)d_in[12];
    const float* ln_w       = (const float*)d_in[13];
    const float* ln_b       = (const float*)d_in[14];
    const float* W_out      = (const float*)d_in[15];
    const int*   scan_path  = (const int*)d_in[16];
    const int*   rev_path   = (const int*)d_in[17];
    (void)scan_path;

    float* ws = (float*)d_ws;
    const size_t S  = (size_t)BB * LL * DI;            // 3,145,728 floats
    const size_t SC = (size_t)NCHUNK * BB * DI * NS;   // 1,572,864 floats
    float* ytslab  = ws + 0 * S;                       // yt_bf (ushort, half used)
    float* zslab   = ws + 1 * S;                       // z_bf (ushort, half used)
    float* duslab  = ws + 2 * S;                       // du (uint, full slab)
    float* btct    = ws + 3 * S;                       // BB*LL*32 floats, packed
    float* chunkA  = btct + (size_t)BB * LL * 32;
    float* chunkB  = chunkA + SC;
    float* bfpool  = chunkB + SC;                      // bf16 staging area

    unsigned short* yt_bf    = (unsigned short*)ytslab;            // ROWS*DI
    unsigned short* z_bf     = (unsigned short*)zslab;             // ROWS*DI
    unsigned int*   du       = (unsigned int*)duslab;              // ROWS*DI uints
    unsigned short* s_bf     = (unsigned short*)bfpool;            // ROWS*DI
    unsigned short* xa_bf    = s_bf + (size_t)ROWS * DI;           // ROWS*DI
    unsigned short* c_bf     = xa_bf + (size_t)ROWS * DI;          // ROWS*DI
    unsigned short* w_out_bf = c_bf + (size_t)ROWS * DI;           // 192*384
    unsigned short* wcomb_bf = w_out_bf + 192 * DI;                // 448*384

    // 1) dual GEMM + embedded prep (R7 form)
    gemm_in<<<dim3(ROWS / 64, 19), 256, 0, stream>>>(
        x, cond, W_in, W_con, x_proj_w, dt_proj_w, W_out,
        xa_bf, z_bf, c_bf, wcomb_bf, w_out_bf);
    // 2) fused depthwise convs (vectorized staging) + silu + scatter
    dwconv2_scatter<<<dim3(64, 12, BB), 256, 0, stream>>>(
        xa_bf, c_bf, conv_w, conv_b, con_conv_w, con_conv_b,
        rev_path, (unsigned short*)du, s_bf);
    // 3) combined GEMM (64x64, 4-buf counted, 896 blocks co-resident)
    gemm_comb<<<dim3(ROWS / 64, NCOMB / 64), 256, 0, stream>>>(
        s_bf, wcomb_bf, dt_proj_b, btct, (unsigned short*)du);
    // 4+5) chunked parallel scan
    scan_chunkA<<<dim3(NCHUNK, DI / 32, BB), 256, 0, stream>>>(
        du, btct, A_logs, chunkA, chunkB);
    scan_chunkC<<<dim3(NCHUNK, DI / 32, BB), 256, 0, stream>>>(
        du, btct, A_logs, Ds, chunkA, chunkB, yt_bf);
    // 6) fused LN + z-mul + out GEMM (32-row tiles, 768 blocks)
    gemm_out_fused<<<dim3(ROWS / 32, DM / 64), 256, 0, stream>>>(
        yt_bf, z_bf, rev_path, ln_w, ln_b, w_out_bf, (float*)d_out);
}